// Round 5
// baseline (280.636 us; speedup 1.0000x reference)
//
#include <hip/hip_runtime.h>

// Modulated deformable conv 3x3, in_ch=out_ch=1, stride=1, pad=1, dil=1.
// B=8, H=W=512. d_in order: depth, mask(weight), offset, w, b.
//
// R11 = R10 resubmit (R10 bench died in harness infra: Trio nursery error,
// no pytest/compile output; kernel re-audited -- alignment, LDS bounds,
// chunk-uniform staging validity all check out).
//
// R10 theory: geometry fix for the latency bound -- 4 px/thread, dwordx4.
//  - R9 post-mortem: inline-asm loads raced (RA spills in-flight asm dest ->
//    replay-dependent divergence). R7/R8: every C-level batching hint was
//    serialized by pressure-aware scheduling (VGPR stuck at 40-44).
//    Conclusion: the 27-load batch is unreachable; stop fighting.
//  - Instead halve exposed latencies per PIXEL: 27 serialized dwordx2 per
//    2px (13.5 lat/px) -> 27 serialized dwordx4 per 4px (6.75 lat/px).
//    Compiler fully owns scheduling (the shape that always passed).
//  - Staging: float4 global loads + ds_write_b128, LDS stride 84 (16B-
//    aligned rows); chunk validity is uniform (tX0,lx4 multiples of 4) so
//    staging is branchless. 3 unrolled rounds.
//  - TX=64, TY=16: 1024 px/block, grid (8,32,8)=2048 blocks = 8/CU.

#define KK 9
#define PAD 1
#define H 512
#define W 512
#define HW (H * W)

#define TX 64
#define TY 16
#define HALO 8
#define LWL (TX + 2 * HALO)              // 80 logical columns
#define LH  (TY + 2 * HALO)              // 32 rows
#define LWS 84                           // storage stride: mult of 4 (b128 LDS writes)
#define NCHUNK (LH * LWL / 4)            // 640 f4 staging chunks
#define SAFE ((LH - 2) * LWS + (LWL - 2))  // 2598: max legit bilinear base index
#define TRASH (LH * LWS)                 // 2688: f4 write-only garbage slot

typedef float f2 __attribute__((ext_vector_type(2)));
typedef float f4 __attribute__((ext_vector_type(4)));

__device__ __forceinline__ float bilin_global(const float* __restrict__ img,
                                              float y, float x) {
    float y0f = floorf(y);
    float x0f = floorf(x);
    int y0 = (int)y0f;
    int x0 = (int)x0f;
    float wy = y - y0f;
    float wx = x - x0f;
    int y1 = y0 + 1;
    int x1 = x0 + 1;

    bool y0i = (y0 >= 0) & (y0 < H);
    bool y1i = (y1 >= 0) & (y1 < H);
    bool x0i = (x0 >= 0) & (x0 < W);
    bool x1i = (x1 >= 0) & (x1 < W);

    int y0c = min(max(y0, 0), H - 1);
    int y1c = min(max(y1, 0), H - 1);
    int x0c = min(max(x0, 0), W - 1);
    int x1c = min(max(x1, 0), W - 1);

    float v00 = (y0i & x0i) ? img[y0c * W + x0c] : 0.0f;
    float v01 = (y0i & x1i) ? img[y0c * W + x1c] : 0.0f;
    float v10 = (y1i & x0i) ? img[y1c * W + x0c] : 0.0f;
    float v11 = (y1i & x1i) ? img[y1c * W + x1c] : 0.0f;

    float omwy = 1.0f - wy;
    float omwx = 1.0f - wx;
    return fmaf(v00 * omwy, omwx,
           fmaf(v01 * omwy, wx,
           fmaf(v10 * wy,   omwx, v11 * wy * wx)));
}

// Branchless tile sample. Coordinates are TILE-RELATIVE floats. Out-of-tile
// lanes read a clamped (safe, garbage) address and set oob; fixup recomputes.
__device__ __forceinline__ float sample_nb(const float* S, float syr, float sxr,
                                           int& oob) {
    const float y0f = floorf(syr);
    const float x0f = floorf(sxr);
    const float wy = syr - y0f;
    const float wx = sxr - x0f;
    const int ly = (int)y0f;
    const int lx = (int)x0f;
    oob |= (int)(((unsigned)ly >= (unsigned)(LH - 1)) |
                 ((unsigned)lx >= (unsigned)(LWL - 1)));
    unsigned su = (unsigned)(ly * LWS + lx);
    su = su < (unsigned)SAFE ? su : (unsigned)SAFE;   // v_min_u32: always-safe read
    const float v00 = S[su];
    const float v01 = S[su + 1];
    const float v10 = S[su + LWS];
    const float v11 = S[su + LWS + 1];
    const float omwy = 1.0f - wy;
    const float omwx = 1.0f - wx;
    return fmaf(v00 * omwy, omwx,
           fmaf(v01 * omwy, wx,
           fmaf(v10 * wy,   omwx, v11 * wy * wx)));
}

__global__ __launch_bounds__(256, 4) void dcn_kernel(
    const float* __restrict__ depth,
    const float* __restrict__ mask,
    const float* __restrict__ offset,
    const float* __restrict__ w9,
    const float* __restrict__ bias,
    float* __restrict__ out) {
    __shared__ float S[LH * LWS + 4];    // +4: f4 TRASH slot

    const int b  = blockIdx.z;
    const int bx = blockIdx.x;
    const int by = blockIdx.y;
    const int tX0 = bx * TX - HALO;      // multiple of 4
    const int tY0 = by * TY - HALO;

    const float* __restrict__ img = depth + (long)b * HW;

    // 4 consecutive px/thread
    const int xq = threadIdx.x & 15;        // x-quad 0..15
    const int yr = threadIdx.x >> 4;        // row 0..15
    const int tx = bx * TX + 4 * xq;
    const int ty = by * TY + yr;
    const int pix = ty * W + tx;

    const float* __restrict__ msk = mask   + ((long)b * KK)     * HW + pix;
    const float* __restrict__ off = offset + ((long)b * 2 * KK) * HW + pix;

    // uniform taps: scalar loads, issued early
    const float wk0 = w9[0], wk1 = w9[1], wk2 = w9[2];
    const float wk3 = w9[3], wk4 = w9[4], wk5 = w9[5];
    const float wk6 = w9[6], wk7 = w9[7], wk8 = w9[8];
    const float bs = bias[0];

    // --- payload: 27 dwordx4 loads (compiler-owned scheduling) ---
    f4 dy0, dy1, dy2, dy3, dy4, dy5, dy6, dy7, dy8;
    f4 dx0, dx1, dx2, dx3, dx4, dx5, dx6, dx7, dx8;
    f4 m0, m1, m2, m3, m4, m5, m6, m7, m8;
#define LDT(k)                                              \
    dy##k = *(const f4*)(off + (2 * k) * HW);               \
    dx##k = *(const f4*)(off + (2 * k + 1) * HW);           \
    m##k  = *(const f4*)(msk + k * HW);
    LDT(0) LDT(1) LDT(2) LDT(3) LDT(4) LDT(5) LDT(6) LDT(7) LDT(8)
#undef LDT

    // --- stage depth tile (+halo): 640 f4 chunks, 3 unrolled rounds.
    // tX0 and lx4 are multiples of 4 and W=512, so each f4 chunk is either
    // fully in-image or fully out -> branchless uniform validity. ---
    #pragma unroll
    for (int j = 0; j < 3; ++j) {
        const int c   = (int)threadIdx.x + j * 256;   // 0..767
        const int ly  = c / 20;                       // 20 chunks per row
        const int lx4 = (c - ly * 20) * 4;
        const int gy  = tY0 + ly;
        const int gx  = tX0 + lx4;
        const int ok  = (int)(((unsigned)gy < (unsigned)H) &
                              ((unsigned)gx < (unsigned)W));
        const f4 v = *(const f4*)(img + (ok ? (gy * W + gx) : 0));
        f4 z;
        z.x = ok ? v.x : 0.0f;
        z.y = ok ? v.y : 0.0f;
        z.z = ok ? v.z : 0.0f;
        z.w = ok ? v.w : 0.0f;
        const int si = (c < NCHUNK) ? (ly * LWS + lx4) : TRASH;
        *(f4*)(S + si) = z;
    }
    __syncthreads();

    float a0 = bs, a1 = bs, a2 = bs, a3 = bs;
    int oob = 0;
    // Tile-relative sample base: (ty - PAD) - tY0 = yr + HALO - PAD
    const float sybr = (float)(yr + HALO - PAD);
    const float sxbr = (float)(4 * xq + HALO - PAD);

    // --- consume: branchless, fully unrolled ---
#define CTAP(k, KYC, KXC, WK)                                                  \
    {                                                                          \
        const float syk = sybr + (float)(KYC);                                 \
        const float sxk = sxbr + (float)(KXC);                                 \
        a0 = fmaf(sample_nb(S, syk + dy##k.x, sxk + 0.0f + dx##k.x, oob),      \
                  m##k.x * (WK), a0);                                          \
        a1 = fmaf(sample_nb(S, syk + dy##k.y, sxk + 1.0f + dx##k.y, oob),      \
                  m##k.y * (WK), a1);                                          \
        a2 = fmaf(sample_nb(S, syk + dy##k.z, sxk + 2.0f + dx##k.z, oob),      \
                  m##k.z * (WK), a2);                                          \
        a3 = fmaf(sample_nb(S, syk + dy##k.w, sxk + 3.0f + dx##k.w, oob),      \
                  m##k.w * (WK), a3);                                          \
    }
    CTAP(0, 0, 0, wk0) CTAP(1, 0, 1, wk1) CTAP(2, 0, 2, wk2)
    CTAP(3, 1, 0, wk3) CTAP(4, 1, 1, wk4) CTAP(5, 1, 2, wk5)
    CTAP(6, 2, 0, wk6) CTAP(7, 2, 1, wk7) CTAP(8, 2, 2, wk8)
#undef CTAP

    // --- rare fixup: lanes with any out-of-tile sample recompute all 4 px
    // via the global path (p ~ 1e-12; wave-uniform skip). ---
    if (__builtin_expect(__any(oob), 0)) {
        if (oob) {
            a0 = bs; a1 = bs; a2 = bs; a3 = bs;
#pragma unroll 1
            for (int k = 0; k < KK; ++k) {
                const int ky = k / 3;
                const int kx = k - 3 * ky;
                const float wk = w9[k];
                const float syb = (float)(ty - PAD + ky);
                const float sxb = (float)(tx - PAD + kx);
#pragma unroll 1
                for (int p = 0; p < 4; ++p) {
                    const float fdy = off[(2 * k) * HW + p];
                    const float fdx = off[(2 * k + 1) * HW + p];
                    const float fm  = msk[k * HW + p];
                    const float sv  = bilin_global(img, syb + fdy,
                                                   sxb + (float)p + fdx);
                    const float add = sv * fm * wk;
                    a0 += (p == 0) ? add : 0.0f;
                    a1 += (p == 1) ? add : 0.0f;
                    a2 += (p == 2) ? add : 0.0f;
                    a3 += (p == 3) ? add : 0.0f;
                }
            }
        }
    }

    f4 r;
    r.x = a0; r.y = a1; r.z = a2; r.w = a3;
    *(f4*)(out + (long)b * HW + pix) = r;
}

extern "C" void kernel_launch(void* const* d_in, const int* in_sizes, int n_in,
                              void* d_out, int out_size, void* d_ws, size_t ws_size,
                              hipStream_t stream) {
    const float* depth  = (const float*)d_in[0];
    const float* mask   = (const float*)d_in[1];   // reference's "weight" arg = modulation mask
    const float* offset = (const float*)d_in[2];
    const float* w9     = (const float*)d_in[3];
    const float* bias   = (const float*)d_in[4];
    float* out = (float*)d_out;

    const int B = in_sizes[0] / HW;   // = 8

    dim3 block(256);
    dim3 grid(W / TX, H / TY, B);     // (8, 32, 8)
    dcn_kernel<<<grid, block, 0, stream>>>(depth, mask, offset, w9, bias, out);
}

// Round 6
// 277.860 us; speedup vs baseline: 1.0100x; 1.0100x over previous
//
#include <hip/hip_runtime.h>

// Modulated deformable conv 3x3, in_ch=out_ch=1, stride=1, pad=1, dil=1.
// B=8, H=W=512. d_in order: depth, mask(weight), offset, w, b.
//
// R12: async global->LDS payload staging (the anti-serialization mechanism).
//  - R6..R11 post-mortem: time == hbm_bytes/achieved_BW in every round;
//    achieved effective BW stuck at ~2.5 TB/s because per-wave MLP ~1-3
//    (VGPR 40-64 across 5 rounds: compiler always serializes VGPR-destined
//    load batches) and occupancy ~50%. Latency hints (sched_barrier, asm
//    pins, raw asm loads) all failed or raced.
//  - Fix: payload (offset+mask = 93% of traffic) staged via
//    __builtin_amdgcn_global_load_lds -- no destination VGPR, so the RA
//    CANNOT serialize it. 27 planes x 256 px staged per block, 27
//    outstanding requests per wave guaranteed, drained once by
//    __syncthreads()'s vmcnt(0).
//  - 1 px/thread, 32x8 blocks, 8192 blocks. LDS 27KB payload + 4.6KB tile
//    = 32.3KB -> 5 blocks/CU (20 waves/CU). Consume: conflict-free
//    ds_read (lane i reads word i of each plane).

#define KK 9
#define PAD 1
#define H 512
#define W 512
#define HW (H * W)

#define TX 32
#define TY 8
#define HALO 8
#define LWL (TX + 2 * HALO)              // 48 tile columns (also storage stride)
#define LH  (TY + 2 * HALO)              // 24 tile rows
#define TILE_N (LH * LWL)                // 1152 tile floats
#define NCHUNK (TILE_N / 4)              // 288 f4 staging chunks
#define SAFE ((LH - 2) * LWL + (LWL - 2))  // 1102: max legit bilinear base idx
#define NPL 27                           // payload planes (18 offset + 9 mask)
#define PL_FLOATS (NPL * 256)            // 6912 floats of payload LDS
#define TILE_OFF PL_FLOATS               // tile starts here
#define TRASH (TILE_OFF + TILE_N)        // f4 write-only garbage slot

typedef float f4 __attribute__((ext_vector_type(4)));

__device__ __forceinline__ void async_ld4(const float* g, float* l) {
    __builtin_amdgcn_global_load_lds(
        (const __attribute__((address_space(1))) void*)g,
        (__attribute__((address_space(3))) void*)l, 4, 0, 0);
}

__device__ __forceinline__ float bilin_global(const float* __restrict__ img,
                                              float y, float x) {
    float y0f = floorf(y);
    float x0f = floorf(x);
    int y0 = (int)y0f;
    int x0 = (int)x0f;
    float wy = y - y0f;
    float wx = x - x0f;
    int y1 = y0 + 1;
    int x1 = x0 + 1;

    bool y0i = (y0 >= 0) & (y0 < H);
    bool y1i = (y1 >= 0) & (y1 < H);
    bool x0i = (x0 >= 0) & (x0 < W);
    bool x1i = (x1 >= 0) & (x1 < W);

    int y0c = min(max(y0, 0), H - 1);
    int y1c = min(max(y1, 0), H - 1);
    int x0c = min(max(x0, 0), W - 1);
    int x1c = min(max(x1, 0), W - 1);

    float v00 = (y0i & x0i) ? img[y0c * W + x0c] : 0.0f;
    float v01 = (y0i & x1i) ? img[y0c * W + x1c] : 0.0f;
    float v10 = (y1i & x0i) ? img[y1c * W + x0c] : 0.0f;
    float v11 = (y1i & x1i) ? img[y1c * W + x1c] : 0.0f;

    float omwy = 1.0f - wy;
    float omwx = 1.0f - wx;
    return fmaf(v00 * omwy, omwx,
           fmaf(v01 * omwy, wx,
           fmaf(v10 * wy,   omwx, v11 * wy * wx)));
}

// Branchless tile sample. Coordinates are TILE-RELATIVE floats. Out-of-tile
// lanes read a clamped (safe, garbage) address and set oob; fixup recomputes.
__device__ __forceinline__ float sample_nb(const float* T, float syr, float sxr,
                                           int& oob) {
    const float y0f = floorf(syr);
    const float x0f = floorf(sxr);
    const float wy = syr - y0f;
    const float wx = sxr - x0f;
    const int ly = (int)y0f;
    const int lx = (int)x0f;
    oob |= (int)(((unsigned)ly >= (unsigned)(LH - 1)) |
                 ((unsigned)lx >= (unsigned)(LWL - 1)));
    unsigned su = (unsigned)(ly * LWL + lx);
    su = su < (unsigned)SAFE ? su : (unsigned)SAFE;   // v_min_u32: always-safe read
    const float v00 = T[su];
    const float v01 = T[su + 1];
    const float v10 = T[su + LWL];
    const float v11 = T[su + LWL + 1];
    const float omwy = 1.0f - wy;
    const float omwx = 1.0f - wx;
    return fmaf(v00 * omwy, omwx,
           fmaf(v01 * omwy, wx,
           fmaf(v10 * wy,   omwx, v11 * wy * wx)));
}

__global__ __launch_bounds__(256, 5) void dcn_kernel(
    const float* __restrict__ depth,
    const float* __restrict__ mask,
    const float* __restrict__ offset,
    const float* __restrict__ w9,
    const float* __restrict__ bias,
    float* __restrict__ out) {
    __shared__ float LDSb[PL_FLOATS + TILE_N + 4];   // 32272 B

    const int b  = blockIdx.z;
    const int bx = blockIdx.x;
    const int by = blockIdx.y;
    const int tX0 = bx * TX - HALO;      // multiple of 4
    const int tY0 = by * TY - HALO;

    const float* __restrict__ img = depth + (long)b * HW;

    const int tid = (int)threadIdx.x;
    const int xc = tid & 31;             // col 0..31
    const int yr = tid >> 5;             // row 0..7
    const int tx = bx * TX + xc;
    const int ty = by * TY + yr;
    const int pix = ty * W + tx;

    const float* __restrict__ offp = offset + ((long)b * 2 * KK) * HW + pix;
    const float* __restrict__ mskp = mask   + ((long)b * KK)     * HW + pix;

    // --- async payload staging: 27 planes x 256 px -> LDS. Fire-and-forget
    // DMA: no dest VGPR, guaranteed 27 outstanding per wave. Slot j holds
    // plane j (0..17 = offset dy0,dx0,dy1,...; 18..26 = mask). Per-wave LDS
    // dest = slot*1KB + wave*256B + lane*4 (dest wave-uniform base). ---
    {
        float* pl = LDSb + (tid >> 6) * 64;          // wave-uniform
        #pragma unroll
        for (int j = 0; j < 18; ++j)
            async_ld4(offp + j * HW, pl + j * 256);
        #pragma unroll
        for (int j = 0; j < 9; ++j)
            async_ld4(mskp + j * HW, pl + (18 + j) * 256);
    }

    // --- depth tile staging (compiler-owned; small): 288 f4 chunks over 2
    // rounds. tX0 and lx4 multiples of 4, W=512 -> chunk validity uniform. ---
    float* T = LDSb + TILE_OFF;
    #pragma unroll
    for (int j = 0; j < 2; ++j) {
        const int c   = tid + j * 256;               // 0..511
        const int ly  = c / 12;                      // 12 chunks per row
        const int lx4 = (c - ly * 12) * 4;
        const int gy  = tY0 + ly;
        const int gx  = tX0 + lx4;
        const int ok  = (int)(((unsigned)gy < (unsigned)H) &
                              ((unsigned)gx < (unsigned)W));
        const f4 v = *(const f4*)(img + (ok ? (gy * W + gx) : 0));
        f4 z;
        z.x = ok ? v.x : 0.0f;
        z.y = ok ? v.y : 0.0f;
        z.z = ok ? v.z : 0.0f;
        z.w = ok ? v.w : 0.0f;
        const int si = (c < NCHUNK) ? (TILE_OFF + ly * LWL + lx4) : TRASH;
        *(f4*)(LDSb + si) = z;
    }

    __syncthreads();   // vmcnt(0)+lgkmcnt(0): payload DMA + tile all landed

    // uniform taps
    const float wk0 = w9[0], wk1 = w9[1], wk2 = w9[2];
    const float wk3 = w9[3], wk4 = w9[4], wk5 = w9[5];
    const float wk6 = w9[6], wk7 = w9[7], wk8 = w9[8];
    const float bs = bias[0];

    float acc = bs;
    int oob = 0;
    // Tile-relative sample base: (ty - PAD) - tY0 = yr + HALO - PAD
    const float sybr = (float)(yr + HALO - PAD);
    const float sxbr = (float)(xc + HALO - PAD);

    // --- consume: payload from LDS (lane i reads word i: conflict-free),
    // sample from LDS tile; branchless, fully unrolled ---
#define CTAP(k, KYC, KXC, WK)                                                  \
    {                                                                          \
        const float dyk = LDSb[(2 * (k)) * 256 + tid];                         \
        const float dxk = LDSb[(2 * (k) + 1) * 256 + tid];                     \
        const float mk  = LDSb[(18 + (k)) * 256 + tid];                        \
        const float sy = sybr + (float)(KYC) + dyk;                            \
        const float sx = sxbr + (float)(KXC) + dxk;                            \
        acc = fmaf(sample_nb(T, sy, sx, oob), mk * (WK), acc);                 \
    }
    CTAP(0, 0, 0, wk0) CTAP(1, 0, 1, wk1) CTAP(2, 0, 2, wk2)
    CTAP(3, 1, 0, wk3) CTAP(4, 1, 1, wk4) CTAP(5, 1, 2, wk5)
    CTAP(6, 2, 0, wk6) CTAP(7, 2, 1, wk7) CTAP(8, 2, 2, wk8)
#undef CTAP

    // --- rare fixup: recompute whole pixel via global path (p ~ 1e-9/sample;
    // wave-uniform skip in the common case). ---
    if (__builtin_expect(__any(oob), 0)) {
        if (oob) {
            acc = bs;
#pragma unroll 1
            for (int k = 0; k < KK; ++k) {
                const int ky = k / 3;
                const int kx = k - 3 * ky;
                const float wk = w9[k];
                const float fdy = offp[(2 * k) * HW];
                const float fdx = offp[(2 * k + 1) * HW];
                const float fm  = mskp[k * HW];
                const float sy = (float)(ty - PAD + ky) + fdy;
                const float sx = (float)(tx - PAD + kx) + fdx;
                acc = fmaf(bilin_global(img, sy, sx), fm * wk, acc);
            }
        }
    }

    out[(long)b * HW + pix] = acc;
}

extern "C" void kernel_launch(void* const* d_in, const int* in_sizes, int n_in,
                              void* d_out, int out_size, void* d_ws, size_t ws_size,
                              hipStream_t stream) {
    const float* depth  = (const float*)d_in[0];
    const float* mask   = (const float*)d_in[1];   // reference's "weight" arg = modulation mask
    const float* offset = (const float*)d_in[2];
    const float* w9     = (const float*)d_in[3];
    const float* bias   = (const float*)d_in[4];
    float* out = (float*)d_out;

    const int B = in_sizes[0] / HW;   // = 8

    dim3 block(256);
    dim3 grid(W / TX, H / TY, B);     // (16, 64, 8)
    dcn_kernel<<<grid, block, 0, stream>>>(depth, mask, offset, w9, bias, out);
}